// Round 5
// baseline (3454.163 us; speedup 1.0000x reference)
//
#include <hip/hip_runtime.h>
#include <hip/hip_bf16.h>

// v5: implicit-GEMM conv3x3(64->256) + bias + GELU + mean. bf16 MFMA 16x16x32.
// Block = (n, PAIR of output rows); grid 64*63 = 4032, 512 threads (8 waves).
// Stage 4 input rows once into LDS (66.5KB -> 2 blocks/CU), ONE barrier, then
// two sequential row-GEMMs reusing the acc registers (nothing held across the
// MFMA loop -> no spill, unlike v4). LDS layout [slot][ciblk][col][8ci]:
// bank = f(col) only -> b128 reads AND writes are minimum-phase conflict-free
// with NO swizzle, and all loop offsets are compile-time ds offset immediates
// (zero addressing VALU in the K-loop). Weights in fragment-linear wb2 as v3.
// acc initialized with bias; gelu'd pixel sums accumulate in gsum[4][4] regs
// across rows/pf; one shuffle-reduce + 64 atomicAdds per block at the end.

typedef __attribute__((ext_vector_type(8))) short short8;
typedef __attribute__((ext_vector_type(4))) float floatx4;
typedef __attribute__((ext_vector_type(4))) unsigned int uintx4;

#define NPAIR 63

__device__ __forceinline__ unsigned int f2bf(float f) {
    unsigned int u = __float_as_uint(f);
    return (u + 0x7FFFu + ((u >> 16) & 1u)) >> 16;   // RNE
}

__device__ __forceinline__ unsigned int pk2(float a, float b) {
    union { __hip_bfloat162 h; unsigned int u; } cv;
    cv.h = __float22bfloat162_rn(make_float2(a, b));  // x=low ci
    return cv.u;
}

__device__ __forceinline__ float gelu_t(float y) {
    float p = __builtin_fmaf(0.044715f, y * y, 1.0f);
    float e = exp2f(-2.3022084f * y * p);
    return y * __builtin_amdgcn_rcpf(1.0f + e);       // y*sigmoid(2*0.79788456*y*p)
}

__global__ __launch_bounds__(256)
void prep_kernel(const float* __restrict__ wgt, float* __restrict__ out,
                 unsigned short* __restrict__ wb2) {
    int g = blockIdx.x * 256 + threadIdx.x;
    if (g < 64 * 256) out[g] = 0.f;                   // zero the atomic target
    if (g < 147456) {                                 // 9 taps * 2 hf * 16 cog * 64 lane * 8
        int j    = g & 7;
        int lane = (g >> 3) & 63;
        int fc   = g >> 9;
        int cog  = fc & 15;
        int half = (fc >> 4) & 1;
        int tap  = fc >> 5;
        int li = lane & 15, quad = lane >> 4;
        int co = cog * 16 + li;
        int ci = half * 32 + quad * 8 + j;
        wb2[g] = (unsigned short)f2bf(wgt[(co * 64 + ci) * 9 + tap]);
    }
}

// LDS index: [slot 0..3][b 0..7][col 0..129][8 ci shorts]
#define XIDX(s, b, c) ((((s) * 8 + (b)) * 130 + (c)) * 8)

__global__ __launch_bounds__(512, 4)
void conv_kernel(const float* __restrict__ x, const float* __restrict__ bias,
                 const unsigned short* __restrict__ wb2, float* __restrict__ out) {
    __shared__ unsigned short xs[4 * 8 * 130 * 8];    // 66560 B -> 2 blocks/CU

    const int bx = blockIdx.x;
    const int n  = bx / NPAIR;
    const int R0 = (bx % NPAIR) * 2;                  // output rows R0, R0+1
    const int tid  = threadIdx.x;
    const int lane = tid & 63;
    const int wave = tid >> 6;
    const int li   = lane & 15;
    const int quad = lane >> 4;
    const int sc = wave & 3;                          // co quarter
    const int sp = wave >> 2;                         // pixel half
    const int coBase  = sc * 64;
    const int pixBase = sp * 64;

    // ---- stage input rows R0..R0+3 (all 64 ci) ----
    {
        const int col = tid & 127;
        const int cig = tid >> 7;                     // ci group of 16
        const float* xg = x + (size_t)n * 64 * 16384
                        + (size_t)cig * 16 * 16384 + R0 * 128 + col;
        const int w0 = XIDX(0, cig * 2, col);
        const int w1 = XIDX(0, cig * 2 + 1, col);
#pragma unroll
        for (int r = 0; r < 4; ++r) {
            float v[16];
#pragma unroll
            for (int k = 0; k < 16; ++k)
                v[k] = xg[(size_t)k * 16384 + r * 128];
            uintx4 p0, p1;
#pragma unroll
            for (int j = 0; j < 4; ++j) {
                p0[j] = pk2(v[2 * j],     v[2 * j + 1]);
                p1[j] = pk2(v[8 + 2 * j], v[9 + 2 * j]);
            }
            *reinterpret_cast<uintx4*>(&xs[w0 + r * 8320]) = p0;  // ds_write_b128
            *reinterpret_cast<uintx4*>(&xs[w1 + r * 8320]) = p1;
        }
    }

    // bias into registers (acc init value); co = coBase + cf*16 + quad*4 + r
    floatx4 bv[4];
#pragma unroll
    for (int cf = 0; cf < 4; ++cf)
        bv[cf] = *reinterpret_cast<const floatx4*>(bias + coBase + cf * 16 + quad * 4);

    floatx4 gs[4];                                    // gelu'd pixel sums [cf][r]
#pragma unroll
    for (int cf = 0; cf < 4; ++cf) gs[cf] = (floatx4){0.f, 0.f, 0.f, 0.f};

    __syncthreads();                                  // the ONLY barrier

    union Frag { uintx4 u; short8 s; };
    const unsigned short* abase = wb2 + (size_t)(sc * 4) * 512 + lane * 8;
    // B base per hf: slot/pf/kw offsets are compile-time immediates
    const unsigned short* bbase0 = &xs[XIDX(0, 0 * 4 + quad, pixBase + li)];
    const unsigned short* bbase1 = &xs[XIDX(0, 1 * 4 + quad, pixBase + li)];

#pragma unroll
    for (int rr = 0; rr < 2; ++rr) {
        floatx4 acc[16];                              // [cf][pf], bias-initialized
#pragma unroll
        for (int cf = 0; cf < 4; ++cf)
#pragma unroll
            for (int pf = 0; pf < 4; ++pf) acc[cf * 4 + pf] = bv[cf];

#pragma unroll
        for (int tap = 0; tap < 9; ++tap) {
            const int kh = tap / 3, kw = tap % 3;
            const int slot = rr + kh;                 // compile-time
#pragma unroll
            for (int hf = 0; hf < 2; ++hf) {
                Frag a[4];
#pragma unroll
                for (int cf = 0; cf < 4; ++cf)
                    a[cf].u = *reinterpret_cast<const uintx4*>(
                        abase + (size_t)(((tap * 2 + hf) * 16) + cf) * 512);
                const unsigned short* bb = hf ? bbase1 : bbase0;
#pragma unroll
                for (int pf = 0; pf < 4; ++pf) {
                    Frag b;
                    b.u = *reinterpret_cast<const uintx4*>(
                        bb + slot * 8320 + (pf * 16 + kw) * 8);   // ds_read_b128, imm offs
#pragma unroll
                    for (int cf = 0; cf < 4; ++cf)
                        acc[cf * 4 + pf] = __builtin_amdgcn_mfma_f32_16x16x32_bf16(
                            a[cf].s, b.s, acc[cf * 4 + pf], 0, 0, 0);
                }
            }
        }

        // accumulate gelu'd pixel sums into gs (no reduction yet)
#pragma unroll
        for (int pf = 0; pf < 4; ++pf) {
            const bool valid = (pixBase + pf * 16 + li) < 126;
#pragma unroll
            for (int cf = 0; cf < 4; ++cf)
#pragma unroll
                for (int r = 0; r < 4; ++r) {
                    float g = gelu_t(acc[cf * 4 + pf][r]);
                    gs[cf][r] += valid ? g : 0.f;     // select: masks garbage cols
                }
        }
    }

    // ---- block epilogue: 16-lane shuffle reduce + atomic mean ----
    const float inv = 1.0f / (126.f * 126.f);
#pragma unroll
    for (int cf = 0; cf < 4; ++cf)
#pragma unroll
        for (int r = 0; r < 4; ++r) {
            float v = gs[cf][r];
            v += __shfl_xor(v, 1);
            v += __shfl_xor(v, 2);
            v += __shfl_xor(v, 4);
            v += __shfl_xor(v, 8);
            if (li == 0)
                atomicAdd(&out[n * 256 + coBase + cf * 16 + quad * 4 + r], v * inv);
        }
}

extern "C" void kernel_launch(void* const* d_in, const int* in_sizes, int n_in,
                              void* d_out, int out_size, void* d_ws, size_t ws_size,
                              hipStream_t stream) {
    const float* x    = (const float*)d_in[0];
    const float* wgt  = (const float*)d_in[1];
    const float* bias = (const float*)d_in[2];
    float* out = (float*)d_out;
    unsigned short* wb2 = (unsigned short*)d_ws;      // 294912 B, fragment-linear bf16

    prep_kernel<<<576, 256, 0, stream>>>(wgt, out, wb2);
    conv_kernel<<<64 * NPAIR, 512, 0, stream>>>(x, bias, wb2, out);
}

// Round 6
// 1893.716 us; speedup vs baseline: 1.8240x; 1.8240x over previous
//
#include <hip/hip_runtime.h>
#include <hip/hip_bf16.h>

// v6: implicit-GEMM conv3x3(64->256) + bias + GELU + mean. bf16 MFMA 16x16x32.
// Recovery from v5's register-spill disaster (WRITE_SIZE 8GB): the ONLY state
// live across the MFMA loop is acc[16] (64 AGPR) + a few scalars, as in the
// proven v3 (64 VGPR + 64 AGPR = exactly the 128-reg cap of (512,4)).
// Block = (n, PAIR of output rows), grid 64*63. Stage 4 input rows once into
// LDS (66.5KB -> 2 blocks/CU), ONE barrier, then two sequential row-GEMMs,
// each with a v3-style transient epilogue (bias load + GELU + mask + 16-lane
// shuffle reduce + atomicAdd) so nothing extra is held across MFMAs.
// LDS layout = v4's PROVEN zero-conflict one: xs[slot][col][64ci] (128B col
// stride) with ci-block rotation swizzle blk_eff=(blk+col)&7; swizzle is
// invariant to pf*16/pixBase mod 8, so B reads use 6 precomputed bases +
// compile-time immediates; slot advance handled by +8320 per row iteration.
// Staging packs with v_cvt_pk_bf16_f32 (pk2). Cols 128/129 zeroed (masked
// outputs read them; zeros keep the MFMA garbage-free).

typedef __attribute__((ext_vector_type(8))) short short8;
typedef __attribute__((ext_vector_type(4))) float floatx4;
typedef __attribute__((ext_vector_type(4))) unsigned int uintx4;

#define NPAIR 63
#define SLOT 8320   // 130 cols * 64 shorts

__device__ __forceinline__ unsigned int f2bf(float f) {
    unsigned int u = __float_as_uint(f);
    return (u + 0x7FFFu + ((u >> 16) & 1u)) >> 16;   // RNE
}

__device__ __forceinline__ unsigned int pk2(float a, float b) {
    union { __hip_bfloat162 h; unsigned int u; } cv;
    cv.h = __float22bfloat162_rn(make_float2(a, b));  // x = low ci
    return cv.u;
}

__device__ __forceinline__ float gelu_t(float y) {
    float p = __builtin_fmaf(0.044715f, y * y, 1.0f);
    float e = exp2f(-2.3022084f * y * p);
    return y * __builtin_amdgcn_rcpf(1.0f + e);       // y*sigmoid(1.5957691*y*p)
}

__global__ __launch_bounds__(256)
void prep_kernel(const float* __restrict__ wgt, float* __restrict__ out,
                 unsigned short* __restrict__ wb2) {
    int g = blockIdx.x * 256 + threadIdx.x;
    if (g < 64 * 256) out[g] = 0.f;                   // zero the atomic target
    if (g < 147456) {                                 // 9 taps * 2 hf * 16 cog * 64 lane * 8
        int j    = g & 7;
        int lane = (g >> 3) & 63;
        int fc   = g >> 9;
        int cog  = fc & 15;
        int half = (fc >> 4) & 1;
        int tap  = fc >> 5;
        int li = lane & 15, quad = lane >> 4;
        int co = cog * 16 + li;
        int ci = half * 32 + quad * 8 + j;
        wb2[g] = (unsigned short)f2bf(wgt[(co * 64 + ci) * 9 + tap]);
    }
}

__global__ __launch_bounds__(512, 4)
void conv_kernel(const float* __restrict__ x, const float* __restrict__ bias,
                 const unsigned short* __restrict__ wb2, float* __restrict__ out) {
    __shared__ unsigned short xs[4 * SLOT];           // 66560 B -> 2 blocks/CU

    const int bx = blockIdx.x;
    const int n  = bx / NPAIR;
    const int R0 = (bx % NPAIR) * 2;                  // output rows R0, R0+1
    const int tid  = threadIdx.x;
    const int lane = tid & 63;
    const int wave = tid >> 6;
    const int li   = lane & 15;
    const int quad = lane >> 4;
    const int sc = wave & 3;                          // co quarter
    const int sp = wave >> 2;                         // pixel half
    const int coBase  = sc * 64;
    const int pixBase = sp * 64;

    // ---- stage input rows R0..R0+3 (all 64 ci) into slots 0..3 ----
    {
        const int col = tid & 127;
        const int cig = tid >> 7;                     // ci group of 16
        const float* xg = x + (size_t)n * 64 * 16384
                        + (size_t)cig * 16 * 16384 + R0 * 128 + col;
        const int w0 = col * 64 + ((cig * 2     + col) & 7) * 8;  // rotation swizzle
        const int w1 = col * 64 + ((cig * 2 + 1 + col) & 7) * 8;
#pragma unroll 1
        for (int r = 0; r < 4; ++r) {
            float v[16];
#pragma unroll
            for (int k = 0; k < 16; ++k)
                v[k] = xg[(size_t)k * 16384 + r * 128];
            uintx4 p0, p1;
#pragma unroll
            for (int j = 0; j < 4; ++j) {
                p0[j] = pk2(v[2 * j],     v[2 * j + 1]);
                p1[j] = pk2(v[8 + 2 * j], v[9 + 2 * j]);
            }
            *reinterpret_cast<uintx4*>(&xs[r * SLOT + w0]) = p0;  // ds_write_b128
            *reinterpret_cast<uintx4*>(&xs[r * SLOT + w1]) = p1;
        }
        // zero cols 128,129 of every slot (read by masked output pixels)
        if (tid < 64) {
            int s = tid >> 4, colx = 128 + ((tid >> 3) & 1), ch = tid & 7;
            *reinterpret_cast<uintx4*>(&xs[s * SLOT + colx * 64 + ch * 8]) =
                (uintx4){0u, 0u, 0u, 0u};
        }
    }

    __syncthreads();                                  // the ONLY barrier

    union Frag { uintx4 u; short8 s; };
    const unsigned short* abase = wb2 + (size_t)(sc * 4) * 512 + lane * 8;
    // B read bases per (hf,kw); swizzle invariant to pixBase/pf (both 0 mod 8)
    int bb[2][3];
#pragma unroll
    for (int hf = 0; hf < 2; ++hf)
#pragma unroll
        for (int kw = 0; kw < 3; ++kw)
            bb[hf][kw] = (pixBase + li + kw) * 64
                       + ((hf * 4 + quad + li + kw) & 7) * 8;

    const float inv = 1.0f / (126.f * 126.f);

#pragma unroll 1
    for (int rr = 0; rr < 2; ++rr) {
        floatx4 acc[16];                              // [cf][pf] — only cross-loop state
#pragma unroll
        for (int i = 0; i < 16; ++i) acc[i] = (floatx4){0.f, 0.f, 0.f, 0.f};

#pragma unroll
        for (int tap = 0; tap < 9; ++tap) {
            const int kh = tap / 3, kw = tap % 3;     // compile-time
#pragma unroll
            for (int hf = 0; hf < 2; ++hf) {
                Frag a[4];
#pragma unroll
                for (int cf = 0; cf < 4; ++cf)
                    a[cf].u = *reinterpret_cast<const uintx4*>(
                        abase + (size_t)(((tap * 2 + hf) * 16) + cf) * 512);
#pragma unroll
                for (int pf = 0; pf < 4; ++pf) {
                    Frag b;                           // slot = rr+kh; kh,pf are imm
                    b.u = *reinterpret_cast<const uintx4*>(
                        &xs[bb[hf][kw] + rr * SLOT + (kh * SLOT + pf * 1024)]);
#pragma unroll
                    for (int cf = 0; cf < 4; ++cf)
                        acc[cf * 4 + pf] = __builtin_amdgcn_mfma_f32_16x16x32_bf16(
                            a[cf].s, b.s, acc[cf * 4 + pf], 0, 0, 0);
                }
            }
        }

        // ---- transient per-row epilogue (v3-style; frees everything) ----
#pragma unroll
        for (int cf = 0; cf < 4; ++cf) {
            const floatx4 bv = *reinterpret_cast<const floatx4*>(
                bias + coBase + cf * 16 + quad * 4);
            floatx4 s = (floatx4){0.f, 0.f, 0.f, 0.f};
#pragma unroll
            for (int pf = 0; pf < 4; ++pf) {
                const bool valid = (pixBase + pf * 16 + li) < 126;
#pragma unroll
                for (int r = 0; r < 4; ++r) {
                    float g = gelu_t(acc[cf * 4 + pf][r] + bv[r]);
                    s[r] += valid ? g : 0.f;
                }
            }
#pragma unroll
            for (int r = 0; r < 4; ++r) {
                float v = s[r];
                v += __shfl_xor(v, 1);
                v += __shfl_xor(v, 2);
                v += __shfl_xor(v, 4);
                v += __shfl_xor(v, 8);
                if (li == 0)
                    atomicAdd(&out[n * 256 + coBase + cf * 16 + quad * 4 + r], v * inv);
            }
        }
    }
}

extern "C" void kernel_launch(void* const* d_in, const int* in_sizes, int n_in,
                              void* d_out, int out_size, void* d_ws, size_t ws_size,
                              hipStream_t stream) {
    const float* x    = (const float*)d_in[0];
    const float* wgt  = (const float*)d_in[1];
    const float* bias = (const float*)d_in[2];
    float* out = (float*)d_out;
    unsigned short* wb2 = (unsigned short*)d_ws;      // 294912 B, fragment-linear bf16

    prep_kernel<<<576, 256, 0, stream>>>(wgt, out, wb2);
    conv_kernel<<<64 * NPAIR, 512, 0, stream>>>(x, bias, wb2, out);
}

// Round 7
// 939.629 us; speedup vs baseline: 3.6761x; 2.0154x over previous
//
#include <hip/hip_runtime.h>
#include <hip/hip_bf16.h>

// v7: implicit-GEMM conv3x3(64->256) + bias + GELU + mean. bf16 MFMA 16x16x32.
// v6 structure (2 output rows/block, 4 staged input rows, one barrier,
// zero-conflict rotated-ci-block LDS layout) + REGISTER SURGERY to kill the
// spill that sank v5/v6 (unified 128-reg cap at launch_bounds(512,4); the
// arch-VGPR half is limited to 64 and overflow spills to scratch):
//   - readfirstlane puts wave-uniform sc/sp/coBase/pixBase in SGPRs
//   - rr fully unrolled (rr*SLOT becomes an immediate)
//   - 3 B-base regs instead of 6: hf=1 base = bb3[kw] ^ 32 shorts
//     (valid because (s+4)&7 == s^4 and the swizzle field is isolated bits)
//   - A fragments loaded in cf-PAIRS (8 live VGPRs, not 16); b[4] reused
// Everything else identical to v6 (proven numerically correct, absmax .0625).

typedef __attribute__((ext_vector_type(8))) short short8;
typedef __attribute__((ext_vector_type(4))) float floatx4;
typedef __attribute__((ext_vector_type(4))) unsigned int uintx4;

#define NPAIR 63
#define SLOT 8320   // 130 cols * 64 shorts

__device__ __forceinline__ unsigned int f2bf(float f) {
    unsigned int u = __float_as_uint(f);
    return (u + 0x7FFFu + ((u >> 16) & 1u)) >> 16;   // RNE
}

__device__ __forceinline__ unsigned int pk2(float a, float b) {
    union { __hip_bfloat162 h; unsigned int u; } cv;
    cv.h = __float22bfloat162_rn(make_float2(a, b));  // x = low ci
    return cv.u;
}

__device__ __forceinline__ float gelu_t(float y) {
    float p = __builtin_fmaf(0.044715f, y * y, 1.0f);
    float e = exp2f(-2.3022084f * y * p);
    return y * __builtin_amdgcn_rcpf(1.0f + e);       // y*sigmoid(1.5957691*y*p)
}

__global__ __launch_bounds__(256)
void prep_kernel(const float* __restrict__ wgt, float* __restrict__ out,
                 unsigned short* __restrict__ wb2) {
    int g = blockIdx.x * 256 + threadIdx.x;
    if (g < 64 * 256) out[g] = 0.f;                   // zero the atomic target
    if (g < 147456) {                                 // 9 taps * 2 hf * 16 cog * 64 lane * 8
        int j    = g & 7;
        int lane = (g >> 3) & 63;
        int fc   = g >> 9;
        int cog  = fc & 15;
        int half = (fc >> 4) & 1;
        int tap  = fc >> 5;
        int li = lane & 15, quad = lane >> 4;
        int co = cog * 16 + li;
        int ci = half * 32 + quad * 8 + j;
        wb2[g] = (unsigned short)f2bf(wgt[(co * 64 + ci) * 9 + tap]);
    }
}

__global__ __launch_bounds__(512, 4)
void conv_kernel(const float* __restrict__ x, const float* __restrict__ bias,
                 const unsigned short* __restrict__ wb2, float* __restrict__ out) {
    __shared__ unsigned short xs[4 * SLOT];           // 66560 B -> 2 blocks/CU

    const int bx = blockIdx.x;
    const int n  = bx / NPAIR;
    const int R0 = (bx % NPAIR) * 2;                  // output rows R0, R0+1
    const int tid  = threadIdx.x;
    const int lane = tid & 63;
    const int li   = lane & 15;
    const int quad = lane >> 4;
    // wave-uniform values -> SGPRs (frees arch VGPRs; enables s-based addressing)
    const int sc = __builtin_amdgcn_readfirstlane((tid >> 6) & 3);
    const int sp = __builtin_amdgcn_readfirstlane(tid >> 8);
    const int coBase  = sc * 64;
    const int pixBase = sp * 64;

    // ---- stage input rows R0..R0+3 (all 64 ci) into slots 0..3 ----
    {
        const int col = tid & 127;
        const int cig = tid >> 7;                     // ci group of 16
        const float* xg = x + (size_t)n * 64 * 16384
                        + (size_t)cig * 16 * 16384 + R0 * 128 + col;
        const int w0 = col * 64 + ((cig * 2     + col) & 7) * 8;  // rotation swizzle
        const int w1 = col * 64 + ((cig * 2 + 1 + col) & 7) * 8;
#pragma unroll 1
        for (int r = 0; r < 4; ++r) {
            float v[16];
#pragma unroll
            for (int k = 0; k < 16; ++k)
                v[k] = xg[(size_t)k * 16384 + r * 128];
            uintx4 p0, p1;
#pragma unroll
            for (int j = 0; j < 4; ++j) {
                p0[j] = pk2(v[2 * j],     v[2 * j + 1]);
                p1[j] = pk2(v[8 + 2 * j], v[9 + 2 * j]);
            }
            *reinterpret_cast<uintx4*>(&xs[r * SLOT + w0]) = p0;  // ds_write_b128
            *reinterpret_cast<uintx4*>(&xs[r * SLOT + w1]) = p1;
        }
        // zero cols 128,129 of every slot (read by masked output pixels)
        if (tid < 64) {
            int s = tid >> 4, colx = 128 + ((tid >> 3) & 1), ch = tid & 7;
            *reinterpret_cast<uintx4*>(&xs[s * SLOT + colx * 64 + ch * 8]) =
                (uintx4){0u, 0u, 0u, 0u};
        }
    }

    __syncthreads();                                  // the ONLY barrier

    union Frag { uintx4 u; short8 s; };
    const unsigned short* abase = wb2 + (size_t)coBase * 32 + lane * 8; // sc*4*512
    // 3 B-read bases (hf=0); hf=1 = base ^ 32 shorts. Swizzle invariant to
    // pixBase/pf (both ≡ 0 mod 8 cols).
    int bb3[3];
#pragma unroll
    for (int kw = 0; kw < 3; ++kw)
        bb3[kw] = (pixBase + li + kw) * 64 + ((quad + li + kw) & 7) * 8;

#pragma unroll
    for (int rr = 0; rr < 2; ++rr) {                  // fully unrolled
        floatx4 acc[16];                              // [cf][pf] — only cross-tap state
#pragma unroll
        for (int i = 0; i < 16; ++i) acc[i] = (floatx4){0.f, 0.f, 0.f, 0.f};

#pragma unroll
        for (int tap = 0; tap < 9; ++tap) {
            const int kh = tap / 3, kw = tap % 3;     // compile-time
#pragma unroll
            for (int hf = 0; hf < 2; ++hf) {
                const int bidx = bb3[kw] ^ (hf * 32); // one v_xor (or nothing)
                Frag b[4];
#pragma unroll
                for (int pf = 0; pf < 4; ++pf)        // (rr+kh)*SLOT, pf*1024: imm
                    b[pf].u = *reinterpret_cast<const uintx4*>(
                        &xs[bidx + (rr + kh) * SLOT + pf * 1024]);
                Frag a0, a1;
                a0.u = *reinterpret_cast<const uintx4*>(
                    abase + (size_t)((tap * 2 + hf) * 16 + 0) * 512);
                a1.u = *reinterpret_cast<const uintx4*>(
                    abase + (size_t)((tap * 2 + hf) * 16 + 1) * 512);
#pragma unroll
                for (int pf = 0; pf < 4; ++pf) {
                    acc[0 * 4 + pf] = __builtin_amdgcn_mfma_f32_16x16x32_bf16(
                        a0.s, b[pf].s, acc[0 * 4 + pf], 0, 0, 0);
                    acc[1 * 4 + pf] = __builtin_amdgcn_mfma_f32_16x16x32_bf16(
                        a1.s, b[pf].s, acc[1 * 4 + pf], 0, 0, 0);
                }
                a0.u = *reinterpret_cast<const uintx4*>(
                    abase + (size_t)((tap * 2 + hf) * 16 + 2) * 512);
                a1.u = *reinterpret_cast<const uintx4*>(
                    abase + (size_t)((tap * 2 + hf) * 16 + 3) * 512);
#pragma unroll
                for (int pf = 0; pf < 4; ++pf) {
                    acc[2 * 4 + pf] = __builtin_amdgcn_mfma_f32_16x16x32_bf16(
                        a0.s, b[pf].s, acc[2 * 4 + pf], 0, 0, 0);
                    acc[3 * 4 + pf] = __builtin_amdgcn_mfma_f32_16x16x32_bf16(
                        a1.s, b[pf].s, acc[3 * 4 + pf], 0, 0, 0);
                }
            }
        }

        // ---- transient per-row epilogue (nothing survives past it) ----
        const float inv = 1.0f / (126.f * 126.f);
#pragma unroll
        for (int cf = 0; cf < 4; ++cf) {
            const floatx4 bv = *reinterpret_cast<const floatx4*>(
                bias + coBase + cf * 16 + quad * 4);
            floatx4 s = (floatx4){0.f, 0.f, 0.f, 0.f};
#pragma unroll
            for (int pf = 0; pf < 4; ++pf) {
                const bool valid = (pixBase + pf * 16 + li) < 126;
#pragma unroll
                for (int r = 0; r < 4; ++r) {
                    float g = gelu_t(acc[cf * 4 + pf][r] + bv[r]);
                    s[r] += valid ? g : 0.f;
                }
            }
#pragma unroll
            for (int r = 0; r < 4; ++r) {
                float v = s[r];
                v += __shfl_xor(v, 1);
                v += __shfl_xor(v, 2);
                v += __shfl_xor(v, 4);
                v += __shfl_xor(v, 8);
                if (li == 0)
                    atomicAdd(&out[n * 256 + coBase + cf * 16 + quad * 4 + r], v * inv);
            }
        }
    }
}

extern "C" void kernel_launch(void* const* d_in, const int* in_sizes, int n_in,
                              void* d_out, int out_size, void* d_ws, size_t ws_size,
                              hipStream_t stream) {
    const float* x    = (const float*)d_in[0];
    const float* wgt  = (const float*)d_in[1];
    const float* bias = (const float*)d_in[2];
    float* out = (float*)d_out;
    unsigned short* wb2 = (unsigned short*)d_ws;      // 294912 B, fragment-linear bf16

    prep_kernel<<<576, 256, 0, stream>>>(wgt, out, wb2);
    conv_kernel<<<64 * NPAIR, 512, 0, stream>>>(x, bias, wb2, out);
}